// Round 3
// baseline (363.895 us; speedup 1.0000x reference)
//
#include <hip/hip_runtime.h>
#include <hip/hip_bf16.h>

#define B_ 2
#define S_ 2048
#define E_ 2048
#define H_ 16
#define D_ 128
#define M_ (B_*S_)
#define NQKV_ (3*E_)

typedef __attribute__((ext_vector_type(8))) short bf16x8;
typedef __attribute__((ext_vector_type(4))) float f32x4;
typedef __attribute__((ext_vector_type(4))) unsigned short u16x4;
typedef __attribute__((ext_vector_type(2))) unsigned u32x2;

__device__ __forceinline__ unsigned short f2bf(float f) {
  union { float f; unsigned u; } v; v.f = f;
  unsigned r = v.u + 0x7fffu + ((v.u >> 16) & 1u);
  return (unsigned short)(r >> 16);
}
__device__ __forceinline__ float bf2f(unsigned short h) {
  union { unsigned u; float f; } v; v.u = ((unsigned)h) << 16;
  return v.f;
}

__device__ __forceinline__ void gload_lds16(const void* g, void* l) {
  __builtin_amdgcn_global_load_lds(
      (const __attribute__((address_space(1))) unsigned*)g,
      (__attribute__((address_space(3))) unsigned*)l, 16, 0, 0);
}

// ---------------------------------------------------------------- prep
__global__ __launch_bounds__(256) void prep_kernel(
    const float* __restrict__ hs,
    const float* __restrict__ Wq, const float* __restrict__ Wk, const float* __restrict__ Wv,
    const float* __restrict__ Wo,
    const float* __restrict__ bq, const float* __restrict__ bk, const float* __restrict__ bv,
    unsigned short* __restrict__ hsb, unsigned short* __restrict__ Wqkv,
    unsigned short* __restrict__ Wob, float* __restrict__ biasqkv,
    float* __restrict__ cosT, float* __restrict__ sinT)
{
  const int seg = blockIdx.y;
  const int t0 = blockIdx.x * 256 + threadIdx.x;
  const int stride = gridDim.x * 256;
  if (seg == 0) {
    const int n = (M_*E_)/4;
    for (int i = t0; i < n; i += stride) {
      f32x4 v = ((const f32x4*)hs)[i];
      u16x4 o; o[0]=f2bf(v[0]); o[1]=f2bf(v[1]); o[2]=f2bf(v[2]); o[3]=f2bf(v[3]);
      ((u16x4*)hsb)[i] = o;
    }
  } else if (seg == 1) {
    const int n = (3*E_*E_)/4;
    for (int i = t0; i < n; i += stride) {
      int e4 = i << 2;
      int r = e4 >> 11;
      int k = e4 & 2047;
      const float* src = (r < E_) ? (Wq + ((size_t)r << 11) + k)
                       : (r < 2*E_) ? (Wk + ((size_t)(r - E_) << 11) + k)
                       : (Wv + ((size_t)(r - 2*E_) << 11) + k);
      f32x4 v = *(const f32x4*)src;
      u16x4 o; o[0]=f2bf(v[0]); o[1]=f2bf(v[1]); o[2]=f2bf(v[2]); o[3]=f2bf(v[3]);
      ((u16x4*)Wqkv)[i] = o;
    }
  } else if (seg == 2) {
    const int n = (E_*E_)/4;
    for (int i = t0; i < n; i += stride) {
      f32x4 v = ((const f32x4*)Wo)[i];
      u16x4 o; o[0]=f2bf(v[0]); o[1]=f2bf(v[1]); o[2]=f2bf(v[2]); o[3]=f2bf(v[3]);
      ((u16x4*)Wob)[i] = o;
    }
  } else if (seg == 3) {
    for (int i = t0; i < NQKV_; i += stride)
      biasqkv[i] = (i < E_) ? bq[i] : (i < 2*E_) ? bk[i - E_] : bv[i - 2*E_];
  } else {
    for (int i = t0; i < S_*64; i += stride) {
      int j = i & 63, s = i >> 6;
      float inv = exp2f(-(float)j * (13.287712379549449f / 64.0f)); // 10000^(-j/64)
      float ang = (float)s * inv;
      cosT[i] = cosf(ang);
      sinT[i] = sinf(ang);
    }
  }
}

// ------------------------------------------------- pipelined GEMM  C = A * B^T + bias
// Tile 256x128, BK=32, 4 waves (2x2, per-wave 128x64), 3 LDS buffers, stage
// depth 2, counted vmcnt(6) never draining to 0 in the main loop (T3+T4).
// BK=32 rows (64 B) make every frag read a contiguous 1 KB => bank-optimal,
// no swizzle needed on either side.
template<int OUT_F32>
__global__ __launch_bounds__(256, 2) void gemm_pipe(
    const unsigned short* __restrict__ A,
    const unsigned short* __restrict__ Bm,
    const float* __restrict__ bias,
    void* __restrict__ Cv,
    int M, int N, int K)
{
  __shared__ __align__(16) unsigned short lA[3][256*32];  // 48 KB
  __shared__ __align__(16) unsigned short lB[3][128*32];  // 24 KB
  const int tid = threadIdx.x;
  const int lane = tid & 63;
  const int w = tid >> 6;
  const int wr = w >> 1, wc = w & 1;
  const int ntile = N >> 7;
  const int tm = blockIdx.x / ntile, tn = blockIdx.x % ntile;
  const int l15 = lane & 15, l4 = lane >> 4;
  const int NT = K >> 5;

  const unsigned short* Abase = A + ((size_t)tm*256)*K;
  const unsigned short* Bbase = Bm + ((size_t)tn*128)*K;

  f32x4 acc[8][4] = {};

  auto stage = [&](int bs, int kt) {
    const unsigned short* Ag = Abase + kt*32;
    #pragma unroll
    for (int i = 0; i < 4; ++i) {
      int cc = i*256 + tid; int row = cc >> 2, col = cc & 3;
      gload_lds16(Ag + (size_t)row*K + col*8, (char*)(&lA[bs][0]) + cc*16);
    }
    const unsigned short* Bg = Bbase + kt*32;
    #pragma unroll
    for (int i = 0; i < 2; ++i) {
      int cc = i*256 + tid; int row = cc >> 2, col = cc & 3;
      gload_lds16(Bg + (size_t)row*K + col*8, (char*)(&lB[bs][0]) + cc*16);
    }
  };

  stage(0, 0);
  stage(1, 1);

  int bufj = 0;
  for (int j = 0; j < NT; ++j) {
    __builtin_amdgcn_sched_barrier(0);
    asm volatile("s_waitcnt lgkmcnt(0)" ::: "memory");
    if (j == NT-1) asm volatile("s_waitcnt vmcnt(0)" ::: "memory");
    else           asm volatile("s_waitcnt vmcnt(6)" ::: "memory");
    __builtin_amdgcn_s_barrier();
    __builtin_amdgcn_sched_barrier(0);
    if (j + 2 < NT) {
      int bs = bufj + 2; if (bs >= 3) bs -= 3;
      stage(bs, j + 2);
    }
    const unsigned short* la = &lA[bufj][0];
    const unsigned short* lb = &lB[bufj][0];
    bf16x8 af[8], bfr[4];
    #pragma unroll
    for (int mt = 0; mt < 8; ++mt)
      af[mt] = *(const bf16x8*)(la + (wr*128 + mt*16 + l15)*32 + l4*8);
    #pragma unroll
    for (int nt = 0; nt < 4; ++nt)
      bfr[nt] = *(const bf16x8*)(lb + (wc*64 + nt*16 + l15)*32 + l4*8);
    #pragma unroll
    for (int mt = 0; mt < 8; ++mt)
      #pragma unroll
      for (int nt = 0; nt < 4; ++nt)
        acc[mt][nt] = __builtin_amdgcn_mfma_f32_16x16x32_bf16(af[mt], bfr[nt], acc[mt][nt], 0, 0, 0);
    ++bufj; if (bufj == 3) bufj = 0;
  }

  #pragma unroll
  for (int mt = 0; mt < 8; ++mt) {
    #pragma unroll
    for (int nt = 0; nt < 4; ++nt) {
      int colg = tn*128 + wc*64 + nt*16 + l15;
      float bvv = bias[colg];
      #pragma unroll
      for (int r = 0; r < 4; ++r) {
        int rowg = tm*256 + wr*128 + mt*16 + l4*4 + r;
        float v = acc[mt][nt][r] + bvv;
        if (OUT_F32) ((float*)Cv)[(size_t)rowg*N + colg] = v;
        else ((unsigned short*)Cv)[(size_t)rowg*N + colg] = f2bf(v);
      }
    }
  }
}

// ---------------------------------------------------------------- RoPE (in-place on qkv)
// q additionally scaled by log2(e)/sqrt(D) so attention works in exp2 domain.
__global__ __launch_bounds__(256) void rope_kernel(
    unsigned short* __restrict__ qkv, const float* __restrict__ cosT, const float* __restrict__ sinT)
{
  int t = blockIdx.x*256 + threadIdx.x;            // M_*H_*64 threads
  int i  = t & 63;
  int h  = (t >> 6) & 15;
  int m  = t >> 10;
  int s  = m & (S_-1);
  float c = cosT[s*64 + i], sn = sinT[s*64 + i];
  const float scale = 0.08838834764831845f * 1.4426950408889634f; // log2e/sqrt(128)
  size_t base = (size_t)m*NQKV_ + h*128;
  float q1 = bf2f(qkv[base+i]), q2 = bf2f(qkv[base+64+i]);
  qkv[base+i]    = f2bf((q1*c - q2*sn)*scale);
  qkv[base+64+i] = f2bf((q2*c + q1*sn)*scale);
  size_t kb = base + E_;
  float k1 = bf2f(qkv[kb+i]), k2 = bf2f(qkv[kb+64+i]);
  qkv[kb+i]    = f2bf(k1*c - k2*sn);
  qkv[kb+64+i] = f2bf(k2*c + k1*sn);
}

// ---------------------------------------------------------------- V transpose -> [B,H,D,S]
__global__ __launch_bounds__(256) void transv_kernel(
    const unsigned short* __restrict__ qkv, unsigned short* __restrict__ Vt)
{
  __shared__ unsigned short t[32][33];
  int bid = blockIdx.x;
  int st = bid & 63;
  int dt = (bid >> 6) & 3;
  int bh = bid >> 8;
  int b = bh >> 4, h = bh & 15;
  int tx = threadIdx.x & 31, ty = threadIdx.x >> 5;
  #pragma unroll
  for (int j = 0; j < 4; ++j) {
    int r = ty + j*8;
    t[r][tx] = qkv[(size_t)(b*S_ + st*32 + r)*NQKV_ + 2*E_ + h*128 + dt*32 + tx];
  }
  __syncthreads();
  #pragma unroll
  for (int j = 0; j < 4; ++j) {
    int r = ty + j*8;
    Vt[((size_t)bh*D_ + dt*32 + r)*S_ + st*32 + tx] = t[tx][r];
  }
}

// ---------------------------------------------------------------- flash attention
__global__ __launch_bounds__(256, 4) void attn_kernel(
    const unsigned short* __restrict__ qkv, const unsigned short* __restrict__ Vt,
    unsigned short* __restrict__ Ao)
{
  __shared__ unsigned short lK[64*128];                 // 16 KB
  __shared__ unsigned short lV[128*64];                 // 16 KB
  __shared__ __align__(16) unsigned short lP[4*16*64];  // 8 KB (bf16 P per wave)
  const int bid = blockIdx.x;
  const int qt = bid & 31;
  const int bh = bid >> 5;
  const int b = bh >> 4, h = bh & 15;
  const int tid = threadIdx.x, lane = tid & 63, w = tid >> 6;
  const int l15 = lane & 15, l4 = lane >> 4;

  const int qrow = qt*64 + w*16 + l15;
  const unsigned short* qp = qkv + (size_t)(b*S_ + qrow)*NQKV_ + h*128 + l4*8;
  bf16x8 qf[4];
  #pragma unroll
  for (int f = 0; f < 4; ++f) qf[f] = *(const bf16x8*)(qp + f*32);

  f32x4 O[8];
  #pragma unroll
  for (int i = 0; i < 8; ++i) O[i] = (f32x4){0.f,0.f,0.f,0.f};
  float m = -1e30f, lsum = 0.f;

  unsigned short* myP = lP + w*(16*64);
  const int ksw = (l15 & 7) << 3;
  const size_t kbase = (size_t)b*S_*NQKV_ + E_ + (size_t)h*128;
  const size_t vbase = (size_t)bh*D_*S_;

  for (int kt = 0; kt < S_; kt += 64) {
    #pragma unroll
    for (int i = 0; i < 4; ++i) {
      int cc = i*256 + tid;
      int row = cc >> 4, col = cc & 15;
      int scol = col ^ (row & 7);
      gload_lds16(qkv + kbase + (size_t)(kt + row)*NQKV_ + scol*8, (char*)lK + cc*16);
    }
    #pragma unroll
    for (int i = 0; i < 4; ++i) {
      int cc = i*256 + tid;
      int row = cc >> 3, col = cc & 7;
      int scol = col ^ ((row & 7) ^ ((row >> 3) & 7));
      gload_lds16(Vt + vbase + (size_t)row*S_ + kt + scol*8, (char*)lV + cc*16);
    }
    asm volatile("s_waitcnt vmcnt(0)" ::: "memory");
    __syncthreads();

    // S^T = K Q^T : sfr[nf][r] = S[key = kt + nf*16 + l4*4 + r][q = l15]
    f32x4 sfr[4];
    #pragma unroll
    for (int nf = 0; nf < 4; ++nf) {
      f32x4 s = (f32x4){0.f,0.f,0.f,0.f};
      #pragma unroll
      for (int ks = 0; ks < 4; ++ks) {
        int row = nf*16 + l15;
        int ch = (ks*4 + l4) ^ (row & 7);
        bf16x8 kf = *(const bf16x8*)(lK + row*128 + ch*8);
        s = __builtin_amdgcn_mfma_f32_16x16x32_bf16(kf, qf[ks], s, 0, 0, 0);
      }
      sfr[nf] = s;
    }

    float vmax = -1e30f;
    #pragma unroll
    for (int nf = 0; nf < 4; ++nf)
      #pragma unroll
      for (int r = 0; r < 4; ++r) vmax = fmaxf(vmax, sfr[nf][r]);
    vmax = fmaxf(vmax, __shfl_xor(vmax, 16, 64));
    vmax = fmaxf(vmax, __shfl_xor(vmax, 32, 64));

    if (__any(vmax > m + 8.0f)) {
      float mn = fmaxf(m, vmax);
      float al = __builtin_amdgcn_exp2f(m - mn);
      m = mn;
      lsum *= al;
      #pragma unroll
      for (int r = 0; r < 4; ++r) {
        float ar = __shfl(al, (lane & 48) + l4*4 + r, 64);
        #pragma unroll
        for (int df = 0; df < 8; ++df) O[df][r] *= ar;
      }
    }

    float ps = 0.f;
    #pragma unroll
    for (int nf = 0; nf < 4; ++nf) {
      #pragma unroll
      for (int r = 0; r < 4; ++r) {
        float p = __builtin_amdgcn_exp2f(sfr[nf][r] - m);
        sfr[nf][r] = p;
        ps += p;
      }
    }
    ps += __shfl_xor(ps, 16, 64);
    ps += __shfl_xor(ps, 32, 64);
    lsum += ps;

    #pragma unroll
    for (int nf = 0; nf < 4; ++nf) {
      unsigned lo = (unsigned)f2bf(sfr[nf][0]) | ((unsigned)f2bf(sfr[nf][1]) << 16);
      unsigned hi = (unsigned)f2bf(sfr[nf][2]) | ((unsigned)f2bf(sfr[nf][3]) << 16);
      int k0 = (nf*16 + l4*4) ^ ksw;
      u32x2 val; val[0] = lo; val[1] = hi;
      *(u32x2*)(myP + l15*64 + k0) = val;
    }
    asm volatile("s_waitcnt lgkmcnt(0)" ::: "memory");

    #pragma unroll
    for (int ks2 = 0; ks2 < 2; ++ks2) {
      int kk = (ks2*32 + l4*8) ^ ksw;
      bf16x8 pf = *(const bf16x8*)(myP + l15*64 + kk);
      #pragma unroll
      for (int df = 0; df < 8; ++df) {
        int row = df*16 + l15;
        int ch = (ks2*4 + l4) ^ ((row & 7) ^ ((row >> 3) & 7));
        bf16x8 vf = *(const bf16x8*)(lV + row*64 + ch*8);
        O[df] = __builtin_amdgcn_mfma_f32_16x16x32_bf16(pf, vf, O[df], 0, 0, 0);
      }
    }
    __syncthreads();
  }

  float linv = 1.0f / lsum;
  float inv[4];
  #pragma unroll
  for (int r = 0; r < 4; ++r) inv[r] = __shfl(linv, (lane & 48) + l4*4 + r, 64);
  #pragma unroll
  for (int df = 0; df < 8; ++df) {
    int colg = h*128 + df*16 + l15;
    #pragma unroll
    for (int r = 0; r < 4; ++r) {
      int rowg = qt*64 + w*16 + l4*4 + r;
      Ao[(size_t)(b*S_ + rowg)*E_ + colg] = f2bf(O[df][r] * inv[r]);
    }
  }
}

// ----------------------------------------------------------------
extern "C" void kernel_launch(void* const* d_in, const int* in_sizes, int n_in,
                              void* d_out, int out_size, void* d_ws, size_t ws_size,
                              hipStream_t stream) {
  const float* hs = (const float*)d_in[0];
  const float* Wq = (const float*)d_in[1];
  const float* bq = (const float*)d_in[2];
  const float* Wk = (const float*)d_in[3];
  const float* bk = (const float*)d_in[4];
  const float* Wv = (const float*)d_in[5];
  const float* bv = (const float*)d_in[6];
  const float* Wo = (const float*)d_in[7];
  const float* bo = (const float*)d_in[8];
  float* out = (float*)d_out;

  char* p = (char*)d_ws;
  auto alloc = [&](size_t bytes) { char* r = p; p += (bytes + 255) & ~(size_t)255; return r; };
  unsigned short* hsb  = (unsigned short*)alloc((size_t)M_*E_*2);
  unsigned short* Wqkv = (unsigned short*)alloc((size_t)NQKV_*E_*2);
  unsigned short* Wob  = (unsigned short*)alloc((size_t)E_*E_*2);
  unsigned short* qkv  = (unsigned short*)alloc((size_t)M_*NQKV_*2);
  unsigned short* Vt   = (unsigned short*)alloc((size_t)B_*H_*D_*S_*2);
  unsigned short* Ao   = (unsigned short*)alloc((size_t)M_*E_*2);
  float* biasqkv = (float*)alloc((size_t)NQKV_*4);
  float* cosT = (float*)alloc((size_t)S_*64*4);
  float* sinT = (float*)alloc((size_t)S_*64*4);

  prep_kernel<<<dim3(2048, 5), 256, 0, stream>>>(hs, Wq, Wk, Wv, Wo, bq, bk, bv,
      hsb, Wqkv, Wob, biasqkv, cosT, sinT);
  gemm_pipe<0><<<dim3((M_/256)*(NQKV_/128)), 256, 0, stream>>>(hsb, Wqkv, biasqkv, qkv, M_, NQKV_, E_);
  rope_kernel<<<dim3((M_*H_*64)/256), 256, 0, stream>>>(qkv, cosT, sinT);
  transv_kernel<<<dim3(B_*H_*(D_/32)*(S_/32)), 256, 0, stream>>>(qkv, Vt);
  attn_kernel<<<dim3(B_*H_*(S_/64)), 256, 0, stream>>>(qkv, Vt, Ao);
  gemm_pipe<1><<<dim3((M_/256)*(E_/128)), 256, 0, stream>>>(Ao, Wob, bo, out, M_, E_, E_);
}

// Round 4
// 319.024 us; speedup vs baseline: 1.1407x; 1.1407x over previous
//
#include <hip/hip_runtime.h>
#include <hip/hip_bf16.h>

#define B_ 2
#define S_ 2048
#define E_ 2048
#define H_ 16
#define D_ 128
#define M_ (B_*S_)
#define NQKV_ (3*E_)

typedef __attribute__((ext_vector_type(8))) short bf16x8;
typedef __attribute__((ext_vector_type(4))) float f32x4;
typedef __attribute__((ext_vector_type(4))) unsigned short u16x4;
typedef __attribute__((ext_vector_type(2))) unsigned u32x2;

__device__ __forceinline__ unsigned short f2bf(float f) {
  union { float f; unsigned u; } v; v.f = f;
  unsigned r = v.u + 0x7fffu + ((v.u >> 16) & 1u);
  return (unsigned short)(r >> 16);
}
__device__ __forceinline__ float bf2f(unsigned short h) {
  union { unsigned u; float f; } v; v.u = ((unsigned)h) << 16;
  return v.f;
}

__device__ __forceinline__ void gload_lds16(const void* g, void* l) {
  __builtin_amdgcn_global_load_lds(
      (const __attribute__((address_space(1))) unsigned*)g,
      (__attribute__((address_space(3))) unsigned*)l, 16, 0, 0);
}

// ---------------------------------------------------------------- prep
__global__ __launch_bounds__(256) void prep_kernel(
    const float* __restrict__ hs,
    const float* __restrict__ Wq, const float* __restrict__ Wk, const float* __restrict__ Wv,
    const float* __restrict__ Wo,
    const float* __restrict__ bq, const float* __restrict__ bk, const float* __restrict__ bv,
    unsigned short* __restrict__ hsb, unsigned short* __restrict__ Wqkv,
    unsigned short* __restrict__ Wob, float* __restrict__ biasqkv,
    float* __restrict__ cosT, float* __restrict__ sinT)
{
  const int seg = blockIdx.y;
  const int t0 = blockIdx.x * 256 + threadIdx.x;
  const int stride = gridDim.x * 256;
  if (seg == 0) {
    const int n = (M_*E_)/4;
    for (int i = t0; i < n; i += stride) {
      f32x4 v = ((const f32x4*)hs)[i];
      u16x4 o; o[0]=f2bf(v[0]); o[1]=f2bf(v[1]); o[2]=f2bf(v[2]); o[3]=f2bf(v[3]);
      ((u16x4*)hsb)[i] = o;
    }
  } else if (seg == 1) {
    const int n = (3*E_*E_)/4;
    for (int i = t0; i < n; i += stride) {
      int e4 = i << 2;
      int r = e4 >> 11;
      int k = e4 & 2047;
      const float* src = (r < E_) ? (Wq + ((size_t)r << 11) + k)
                       : (r < 2*E_) ? (Wk + ((size_t)(r - E_) << 11) + k)
                       : (Wv + ((size_t)(r - 2*E_) << 11) + k);
      f32x4 v = *(const f32x4*)src;
      u16x4 o; o[0]=f2bf(v[0]); o[1]=f2bf(v[1]); o[2]=f2bf(v[2]); o[3]=f2bf(v[3]);
      ((u16x4*)Wqkv)[i] = o;
    }
  } else if (seg == 2) {
    const int n = (E_*E_)/4;
    for (int i = t0; i < n; i += stride) {
      f32x4 v = ((const f32x4*)Wo)[i];
      u16x4 o; o[0]=f2bf(v[0]); o[1]=f2bf(v[1]); o[2]=f2bf(v[2]); o[3]=f2bf(v[3]);
      ((u16x4*)Wob)[i] = o;
    }
  } else if (seg == 3) {
    for (int i = t0; i < NQKV_; i += stride)
      biasqkv[i] = (i < E_) ? bq[i] : (i < 2*E_) ? bk[i - E_] : bv[i - 2*E_];
  } else {
    for (int i = t0; i < S_*64; i += stride) {
      int j = i & 63, s = i >> 6;
      float inv = exp2f(-(float)j * (13.287712379549449f / 64.0f)); // 10000^(-j/64)
      float ang = (float)s * inv;
      cosT[i] = cosf(ang);
      sinT[i] = sinf(ang);
    }
  }
}

// ================================================================ 8-phase 256^2 GEMM
// C = A * B^T + bias, bf16 out. 512 threads (8 waves 2Mx4N), BK=64, LDS 128KB:
// [buf][A|B][ks] four 16KB blocks of [256 rows][32 cols]. Counted vmcnt(6),
// never drained in main loop. Swizzle: 16B chunk ^= (row>>1)&3 (2-way = free).
#define STAGE8(basePtr, BUF, AB, KS, KT) do { \
    unsigned short* dst_ = lds + (BUF)*32768 + (AB)*16384 + (KS)*8192; \
    const unsigned short* src_ = (basePtr) + (KT)*64 + (KS)*32; \
    _Pragma("unroll") \
    for (int j_ = 0; j_ < 2; ++j_) { \
      int cc_ = (j_ << 9) + tid; \
      int row_ = cc_ >> 2, c2_ = cc_ & 3; \
      int sc_ = c2_ ^ ((row_ >> 1) & 3); \
      gload_lds16(src_ + (size_t)row_*K + sc_*8, (char*)dst_ + cc_*16); \
    } } while(0)

#define LOADA8(MH, KS, BUF) do { \
    const unsigned short* Ab_ = lds + (BUF)*32768 + (KS)*8192; \
    _Pragma("unroll") \
    for (int j_ = 0; j_ < 4; ++j_) { \
      int row_ = wr*128 + ((MH)*4 + j_)*16 + l15; \
      af[j_] = *(const bf16x8*)(Ab_ + row_*32 + ((l4 ^ ((row_>>1)&3)) << 3)); \
    } } while(0)

#define LOADB8(KS, BUF) do { \
    const unsigned short* Bb_ = lds + (BUF)*32768 + 16384 + (KS)*8192; \
    _Pragma("unroll") \
    for (int j_ = 0; j_ < 4; ++j_) { \
      int row_ = wc*64 + j_*16 + l15; \
      bf[j_] = *(const bf16x8*)(Bb_ + row_*32 + ((l4 ^ ((row_>>1)&3)) << 3)); \
    } } while(0)

#define MFMAQ8(MH) do { \
    _Pragma("unroll") \
    for (int mm_ = 0; mm_ < 4; ++mm_) \
      _Pragma("unroll") \
      for (int nn_ = 0; nn_ < 4; ++nn_) \
        acc[(MH)*4+mm_][nn_] = __builtin_amdgcn_mfma_f32_16x16x32_bf16(af[mm_], bf[nn_], acc[(MH)*4+mm_][nn_], 0,0,0); \
    } while(0)

#define VMW6 do { if (nl) asm volatile("s_waitcnt vmcnt(6)" ::: "memory"); \
                  else    asm volatile("s_waitcnt vmcnt(0)" ::: "memory"); } while(0)
#define VMNONE do {} while(0)

#define PHASE8(MH, KS, BUF, ISSUE, WAITV) do { \
    LOADA8(MH, KS, BUF); \
    if ((MH) == 0) LOADB8(KS, BUF); \
    ISSUE; \
    __builtin_amdgcn_sched_barrier(0); \
    __builtin_amdgcn_s_barrier(); \
    asm volatile("s_waitcnt lgkmcnt(0)" ::: "memory"); \
    __builtin_amdgcn_sched_barrier(0); \
    __builtin_amdgcn_s_setprio(1); \
    MFMAQ8(MH); \
    __builtin_amdgcn_s_setprio(0); \
    __builtin_amdgcn_sched_barrier(0); \
    WAITV; \
    __builtin_amdgcn_s_barrier(); \
  } while(0)

__global__ __launch_bounds__(512, 2) void gemm8(
    const unsigned short* __restrict__ A,
    const unsigned short* __restrict__ Bm,
    const float* __restrict__ bias,
    unsigned short* __restrict__ Cv,
    int M, int N, int K)
{
  __shared__ __align__(16) unsigned short lds[65536];   // 128 KB
  const int tid = threadIdx.x;
  const int lane = tid & 63;
  const int w = tid >> 6;             // 0..7
  const int wr = w >> 2, wc = w & 3;  // 2 x 4
  const int l15 = lane & 15, l4 = lane >> 4;

  const int ntile = N >> 8;
  int wg = blockIdx.x;
  const int cpx = gridDim.x >> 3;     // grid % 8 == 0 for our shapes
  wg = (wg & 7) * cpx + (wg >> 3);
  const int tm = wg / ntile, tn = wg % ntile;

  const unsigned short* Abase = A + ((size_t)tm*256)*K;
  const unsigned short* Bbase = Bm + ((size_t)tn*256)*K;

  f32x4 acc[8][4] = {};
  bf16x8 af[4], bf[4];

  const int NITER = K >> 7;   // 2 K-tiles (BK=64) per iteration

  // Prologue: t0's 4 halves + t1's first 3 halves, retire t0 fully.
  STAGE8(Bbase, 0, 1, 0, 0); STAGE8(Abase, 0, 0, 0, 0);
  STAGE8(Bbase, 0, 1, 1, 0); STAGE8(Abase, 0, 0, 1, 0);
  STAGE8(Bbase, 1, 1, 0, 1); STAGE8(Abase, 1, 0, 0, 1);
  STAGE8(Bbase, 1, 1, 1, 1);
  __builtin_amdgcn_sched_barrier(0);
  asm volatile("s_waitcnt vmcnt(6)" ::: "memory");
  __builtin_amdgcn_s_barrier();

  for (int i = 0; i < NITER; ++i) {
    const int t1k = 2*i + 1, t2k = 2*i + 2, t3k = 2*i + 3;
    const bool nl = (i < NITER - 1);
    PHASE8(0, 0, 0, STAGE8(Abase, 1, 0, 1, t1k), VMNONE);            // P1
    PHASE8(1, 0, 0, if (nl) STAGE8(Bbase, 0, 1, 0, t2k), VMNONE);    // P2
    PHASE8(0, 1, 0, if (nl) STAGE8(Abase, 0, 0, 0, t2k), VMNONE);    // P3
    PHASE8(1, 1, 0, if (nl) STAGE8(Bbase, 0, 1, 1, t2k), VMW6);      // P4
    PHASE8(0, 0, 1, if (nl) STAGE8(Abase, 0, 0, 1, t2k), VMNONE);    // P5
    PHASE8(1, 0, 1, if (nl) STAGE8(Bbase, 1, 1, 0, t3k), VMNONE);    // P6
    PHASE8(0, 1, 1, if (nl) STAGE8(Abase, 1, 0, 0, t3k), VMNONE);    // P7
    PHASE8(1, 1, 1, if (nl) STAGE8(Bbase, 1, 1, 1, t3k), VMW6);      // P8
  }

  #pragma unroll
  for (int mt = 0; mt < 8; ++mt) {
    #pragma unroll
    for (int nt = 0; nt < 4; ++nt) {
      int colg = tn*256 + wc*64 + nt*16 + l15;
      float bvv = bias[colg];
      #pragma unroll
      for (int r = 0; r < 4; ++r) {
        int rowg = tm*256 + wr*128 + mt*16 + l4*4 + r;
        Cv[(size_t)rowg*N + colg] = f2bf(acc[mt][nt][r] + bvv);
      }
    }
  }
}

// ------------------------------------------------- GEMM  C = A * B^T + bias (128^2, known-good)
template<int OUT_F32>
__global__ __launch_bounds__(256) void gemm_bt(
    const unsigned short* __restrict__ A,
    const unsigned short* __restrict__ Bm,
    const float* __restrict__ bias,
    void* __restrict__ Cv,
    int M, int N, int K)
{
  __shared__ unsigned short lA[128*64];
  __shared__ unsigned short lB[128*64];
  const int tid = threadIdx.x;
  const int lane = tid & 63;
  const int w = tid >> 6;
  const int wr = w >> 1, wc = w & 1;
  const int ntile = N >> 7;
  const int tm = blockIdx.x / ntile, tn = blockIdx.x % ntile;
  const int l15 = lane & 15, l4 = lane >> 4;

  f32x4 acc[4][4] = {};

  for (int kt = 0; kt < K; kt += 64) {
    #pragma unroll
    for (int i = 0; i < 4; ++i) {
      int cc = i*256 + tid;
      int row = cc >> 3, col = cc & 7;
      int scol = col ^ (row & 7);
      gload_lds16(A + (size_t)(tm*128 + row)*K + kt + scol*8, (char*)lA + cc*16);
    }
    #pragma unroll
    for (int i = 0; i < 4; ++i) {
      int cc = i*256 + tid;
      int row = cc >> 3, col = cc & 7;
      int scol = col ^ (row & 7);
      gload_lds16(Bm + (size_t)(tn*128 + row)*K + kt + scol*8, (char*)lB + cc*16);
    }
    asm volatile("s_waitcnt vmcnt(0)" ::: "memory");
    __syncthreads();

    #pragma unroll
    for (int ks = 0; ks < 2; ++ks) {
      bf16x8 af[4], bfr[4];
      #pragma unroll
      for (int mt = 0; mt < 4; ++mt) {
        int row = wr*64 + mt*16 + l15;
        int ch = (ks*4 + l4) ^ (row & 7);
        af[mt] = *(const bf16x8*)(lA + row*64 + ch*8);
      }
      #pragma unroll
      for (int nt = 0; nt < 4; ++nt) {
        int row = wc*64 + nt*16 + l15;
        int ch = (ks*4 + l4) ^ (row & 7);
        bfr[nt] = *(const bf16x8*)(lB + row*64 + ch*8);
      }
      #pragma unroll
      for (int mt = 0; mt < 4; ++mt)
        #pragma unroll
        for (int nt = 0; nt < 4; ++nt)
          acc[mt][nt] = __builtin_amdgcn_mfma_f32_16x16x32_bf16(af[mt], bfr[nt], acc[mt][nt], 0, 0, 0);
    }
    __syncthreads();
  }

  #pragma unroll
  for (int mt = 0; mt < 4; ++mt) {
    #pragma unroll
    for (int nt = 0; nt < 4; ++nt) {
      int colg = tn*128 + wc*64 + nt*16 + l15;
      float bvv = bias[colg];
      #pragma unroll
      for (int r = 0; r < 4; ++r) {
        int rowg = tm*128 + wr*64 + mt*16 + l4*4 + r;
        float v = acc[mt][nt][r] + bvv;
        if (OUT_F32) ((float*)Cv)[(size_t)rowg*N + colg] = v;
        else ((unsigned short*)Cv)[(size_t)rowg*N + colg] = f2bf(v);
      }
    }
  }
}

// ---------------------------------------------------------------- RoPE (in-place on qkv)
// q additionally scaled by log2(e)/sqrt(D) so attention works in exp2 domain.
__global__ __launch_bounds__(256) void rope_kernel(
    unsigned short* __restrict__ qkv, const float* __restrict__ cosT, const float* __restrict__ sinT)
{
  int t = blockIdx.x*256 + threadIdx.x;            // M_*H_*64 threads
  int i  = t & 63;
  int h  = (t >> 6) & 15;
  int m  = t >> 10;
  int s  = m & (S_-1);
  float c = cosT[s*64 + i], sn = sinT[s*64 + i];
  const float scale = 0.08838834764831845f * 1.4426950408889634f; // log2e/sqrt(128)
  size_t base = (size_t)m*NQKV_ + h*128;
  float q1 = bf2f(qkv[base+i]), q2 = bf2f(qkv[base+64+i]);
  qkv[base+i]    = f2bf((q1*c - q2*sn)*scale);
  qkv[base+64+i] = f2bf((q2*c + q1*sn)*scale);
  size_t kb = base + E_;
  float k1 = bf2f(qkv[kb+i]), k2 = bf2f(qkv[kb+64+i]);
  qkv[kb+i]    = f2bf(k1*c - k2*sn);
  qkv[kb+64+i] = f2bf(k2*c + k1*sn);
}

// ---------------------------------------------------------------- V transpose -> [B,H,D,S]
__global__ __launch_bounds__(256) void transv_kernel(
    const unsigned short* __restrict__ qkv, unsigned short* __restrict__ Vt)
{
  __shared__ unsigned short t[32][33];
  int bid = blockIdx.x;
  int st = bid & 63;
  int dt = (bid >> 6) & 3;
  int bh = bid >> 8;
  int b = bh >> 4, h = bh & 15;
  int tx = threadIdx.x & 31, ty = threadIdx.x >> 5;
  #pragma unroll
  for (int j = 0; j < 4; ++j) {
    int r = ty + j*8;
    t[r][tx] = qkv[(size_t)(b*S_ + st*32 + r)*NQKV_ + 2*E_ + h*128 + dt*32 + tx];
  }
  __syncthreads();
  #pragma unroll
  for (int j = 0; j < 4; ++j) {
    int r = ty + j*8;
    Vt[((size_t)bh*D_ + dt*32 + r)*S_ + st*32 + tx] = t[tx][r];
  }
}

// ---------------------------------------------------------------- flash attention
__global__ __launch_bounds__(256, 4) void attn_kernel(
    const unsigned short* __restrict__ qkv, const unsigned short* __restrict__ Vt,
    unsigned short* __restrict__ Ao)
{
  __shared__ unsigned short lK[64*128];                 // 16 KB
  __shared__ unsigned short lV[128*64];                 // 16 KB
  __shared__ __align__(16) unsigned short lP[4*16*64];  // 8 KB (bf16 P per wave)
  const int bid = blockIdx.x;
  const int qt = bid & 31;
  const int bh = bid >> 5;
  const int b = bh >> 4, h = bh & 15;
  const int tid = threadIdx.x, lane = tid & 63, w = tid >> 6;
  const int l15 = lane & 15, l4 = lane >> 4;

  const int qrow = qt*64 + w*16 + l15;
  const unsigned short* qp = qkv + (size_t)(b*S_ + qrow)*NQKV_ + h*128 + l4*8;
  bf16x8 qf[4];
  #pragma unroll
  for (int f = 0; f < 4; ++f) qf[f] = *(const bf16x8*)(qp + f*32);

  f32x4 O[8];
  #pragma unroll
  for (int i = 0; i < 8; ++i) O[i] = (f32x4){0.f,0.f,0.f,0.f};
  float m = -1e30f, lsum = 0.f;

  unsigned short* myP = lP + w*(16*64);
  const int ksw = (l15 & 7) << 3;
  const size_t kbase = (size_t)b*S_*NQKV_ + E_ + (size_t)h*128;
  const size_t vbase = (size_t)bh*D_*S_;

  for (int kt = 0; kt < S_; kt += 64) {
    #pragma unroll
    for (int i = 0; i < 4; ++i) {
      int cc = i*256 + tid;
      int row = cc >> 4, col = cc & 15;
      int scol = col ^ (row & 7);
      gload_lds16(qkv + kbase + (size_t)(kt + row)*NQKV_ + scol*8, (char*)lK + cc*16);
    }
    #pragma unroll
    for (int i = 0; i < 4; ++i) {
      int cc = i*256 + tid;
      int row = cc >> 3, col = cc & 7;
      int scol = col ^ ((row & 7) ^ ((row >> 3) & 7));
      gload_lds16(Vt + vbase + (size_t)row*S_ + kt + scol*8, (char*)lV + cc*16);
    }
    asm volatile("s_waitcnt vmcnt(0)" ::: "memory");
    __syncthreads();

    // S^T = K Q^T : sfr[nf][r] = S[key = kt + nf*16 + l4*4 + r][q = l15]
    f32x4 sfr[4];
    #pragma unroll
    for (int nf = 0; nf < 4; ++nf) {
      f32x4 s = (f32x4){0.f,0.f,0.f,0.f};
      #pragma unroll
      for (int ks = 0; ks < 4; ++ks) {
        int row = nf*16 + l15;
        int ch = (ks*4 + l4) ^ (row & 7);
        bf16x8 kf = *(const bf16x8*)(lK + row*128 + ch*8);
        s = __builtin_amdgcn_mfma_f32_16x16x32_bf16(kf, qf[ks], s, 0, 0, 0);
      }
      sfr[nf] = s;
    }

    float vmax = -1e30f;
    #pragma unroll
    for (int nf = 0; nf < 4; ++nf)
      #pragma unroll
      for (int r = 0; r < 4; ++r) vmax = fmaxf(vmax, sfr[nf][r]);
    vmax = fmaxf(vmax, __shfl_xor(vmax, 16, 64));
    vmax = fmaxf(vmax, __shfl_xor(vmax, 32, 64));

    if (__any(vmax > m + 8.0f)) {
      float mn = fmaxf(m, vmax);
      float al = __builtin_amdgcn_exp2f(m - mn);
      m = mn;
      lsum *= al;
      #pragma unroll
      for (int r = 0; r < 4; ++r) {
        float ar = __shfl(al, (lane & 48) + l4*4 + r, 64);
        #pragma unroll
        for (int df = 0; df < 8; ++df) O[df][r] *= ar;
      }
    }

    float ps = 0.f;
    #pragma unroll
    for (int nf = 0; nf < 4; ++nf) {
      #pragma unroll
      for (int r = 0; r < 4; ++r) {
        float p = __builtin_amdgcn_exp2f(sfr[nf][r] - m);
        sfr[nf][r] = p;
        ps += p;
      }
    }
    ps += __shfl_xor(ps, 16, 64);
    ps += __shfl_xor(ps, 32, 64);
    lsum += ps;

    #pragma unroll
    for (int nf = 0; nf < 4; ++nf) {
      unsigned lo = (unsigned)f2bf(sfr[nf][0]) | ((unsigned)f2bf(sfr[nf][1]) << 16);
      unsigned hi = (unsigned)f2bf(sfr[nf][2]) | ((unsigned)f2bf(sfr[nf][3]) << 16);
      int k0 = (nf*16 + l4*4) ^ ksw;
      u32x2 val; val[0] = lo; val[1] = hi;
      *(u32x2*)(myP + l15*64 + k0) = val;
    }
    asm volatile("s_waitcnt lgkmcnt(0)" ::: "memory");

    #pragma unroll
    for (int ks2 = 0; ks2 < 2; ++ks2) {
      int kk = (ks2*32 + l4*8) ^ ksw;
      bf16x8 pf = *(const bf16x8*)(myP + l15*64 + kk);
      #pragma unroll
      for (int df = 0; df < 8; ++df) {
        int row = df*16 + l15;
        int ch = (ks2*4 + l4) ^ ((row & 7) ^ ((row >> 3) & 7));
        bf16x8 vf = *(const bf16x8*)(lV + row*64 + ch*8);
        O[df] = __builtin_amdgcn_mfma_f32_16x16x32_bf16(pf, vf, O[df], 0, 0, 0);
      }
    }
    __syncthreads();
  }

  float linv = 1.0f / lsum;
  float inv[4];
  #pragma unroll
  for (int r = 0; r < 4; ++r) inv[r] = __shfl(linv, (lane & 48) + l4*4 + r, 64);
  #pragma unroll
  for (int df = 0; df < 8; ++df) {
    int colg = h*128 + df*16 + l15;
    #pragma unroll
    for (int r = 0; r < 4; ++r) {
      int rowg = qt*64 + w*16 + l4*4 + r;
      Ao[(size_t)(b*S_ + rowg)*E_ + colg] = f2bf(O[df][r] * inv[r]);
    }
  }
}

// ----------------------------------------------------------------
extern "C" void kernel_launch(void* const* d_in, const int* in_sizes, int n_in,
                              void* d_out, int out_size, void* d_ws, size_t ws_size,
                              hipStream_t stream) {
  const float* hs = (const float*)d_in[0];
  const float* Wq = (const float*)d_in[1];
  const float* bq = (const float*)d_in[2];
  const float* Wk = (const float*)d_in[3];
  const float* bk = (const float*)d_in[4];
  const float* Wv = (const float*)d_in[5];
  const float* bv = (const float*)d_in[6];
  const float* Wo = (const float*)d_in[7];
  const float* bo = (const float*)d_in[8];
  float* out = (float*)d_out;

  char* p = (char*)d_ws;
  auto alloc = [&](size_t bytes) { char* r = p; p += (bytes + 255) & ~(size_t)255; return r; };
  unsigned short* hsb  = (unsigned short*)alloc((size_t)M_*E_*2);
  unsigned short* Wqkv = (unsigned short*)alloc((size_t)NQKV_*E_*2);
  unsigned short* Wob  = (unsigned short*)alloc((size_t)E_*E_*2);
  unsigned short* qkv  = (unsigned short*)alloc((size_t)M_*NQKV_*2);
  unsigned short* Vt   = (unsigned short*)alloc((size_t)B_*H_*D_*S_*2);
  unsigned short* Ao   = (unsigned short*)alloc((size_t)M_*E_*2);
  float* biasqkv = (float*)alloc((size_t)NQKV_*4);
  float* cosT = (float*)alloc((size_t)S_*64*4);
  float* sinT = (float*)alloc((size_t)S_*64*4);

  prep_kernel<<<dim3(2048, 5), 256, 0, stream>>>(hs, Wq, Wk, Wv, Wo, bq, bk, bv,
      hsb, Wqkv, Wob, biasqkv, cosT, sinT);
  gemm8<<<dim3((M_/256)*(NQKV_/256)), 512, 0, stream>>>(hsb, Wqkv, biasqkv, qkv, M_, NQKV_, E_);
  rope_kernel<<<dim3((M_*H_*64)/256), 256, 0, stream>>>(qkv, cosT, sinT);
  transv_kernel<<<dim3(B_*H_*(D_/32)*(S_/32)), 256, 0, stream>>>(qkv, Vt);
  attn_kernel<<<dim3(B_*H_*(S_/64)), 256, 0, stream>>>(qkv, Vt, Ao);
  gemm_bt<1><<<dim3((M_/128)*(E_/128)), 256, 0, stream>>>(Ao, Wob, bo, out, M_, E_, E_);
}

// Round 5
// 318.095 us; speedup vs baseline: 1.1440x; 1.0029x over previous
//
#include <hip/hip_runtime.h>
#include <hip/hip_bf16.h>

#define B_ 2
#define S_ 2048
#define E_ 2048
#define H_ 16
#define D_ 128
#define M_ (B_*S_)
#define NQKV_ (3*E_)

typedef __attribute__((ext_vector_type(8))) short bf16x8;
typedef __attribute__((ext_vector_type(4))) float f32x4;
typedef __attribute__((ext_vector_type(4))) unsigned short u16x4;
typedef __attribute__((ext_vector_type(2))) unsigned u32x2;

__device__ __forceinline__ unsigned short f2bf(float f) {
  union { float f; unsigned u; } v; v.f = f;
  unsigned r = v.u + 0x7fffu + ((v.u >> 16) & 1u);
  return (unsigned short)(r >> 16);
}
__device__ __forceinline__ float bf2f(unsigned short h) {
  union { unsigned u; float f; } v; v.u = ((unsigned)h) << 16;
  return v.f;
}

__device__ __forceinline__ void gload_lds16(const void* g, void* l) {
  __builtin_amdgcn_global_load_lds(
      (const __attribute__((address_space(1))) unsigned*)g,
      (__attribute__((address_space(3))) unsigned*)l, 16, 0, 0);
}

// ---------------------------------------------------------------- prep
__global__ __launch_bounds__(256) void prep_kernel(
    const float* __restrict__ hs,
    const float* __restrict__ Wq, const float* __restrict__ Wk, const float* __restrict__ Wv,
    const float* __restrict__ Wo,
    const float* __restrict__ bq, const float* __restrict__ bk, const float* __restrict__ bv,
    unsigned short* __restrict__ hsb, unsigned short* __restrict__ Wqkv,
    unsigned short* __restrict__ Wob, float* __restrict__ biasqkv,
    float* __restrict__ cosT, float* __restrict__ sinT)
{
  const int seg = blockIdx.y;
  const int t0 = blockIdx.x * 256 + threadIdx.x;
  const int stride = gridDim.x * 256;
  if (seg == 0) {
    const int n = (M_*E_)/4;
    for (int i = t0; i < n; i += stride) {
      f32x4 v = ((const f32x4*)hs)[i];
      u16x4 o; o[0]=f2bf(v[0]); o[1]=f2bf(v[1]); o[2]=f2bf(v[2]); o[3]=f2bf(v[3]);
      ((u16x4*)hsb)[i] = o;
    }
  } else if (seg == 1) {
    const int n = (3*E_*E_)/4;
    for (int i = t0; i < n; i += stride) {
      int e4 = i << 2;
      int r = e4 >> 11;
      int k = e4 & 2047;
      const float* src = (r < E_) ? (Wq + ((size_t)r << 11) + k)
                       : (r < 2*E_) ? (Wk + ((size_t)(r - E_) << 11) + k)
                       : (Wv + ((size_t)(r - 2*E_) << 11) + k);
      f32x4 v = *(const f32x4*)src;
      u16x4 o; o[0]=f2bf(v[0]); o[1]=f2bf(v[1]); o[2]=f2bf(v[2]); o[3]=f2bf(v[3]);
      ((u16x4*)Wqkv)[i] = o;
    }
  } else if (seg == 2) {
    const int n = (E_*E_)/4;
    for (int i = t0; i < n; i += stride) {
      f32x4 v = ((const f32x4*)Wo)[i];
      u16x4 o; o[0]=f2bf(v[0]); o[1]=f2bf(v[1]); o[2]=f2bf(v[2]); o[3]=f2bf(v[3]);
      ((u16x4*)Wob)[i] = o;
    }
  } else if (seg == 3) {
    for (int i = t0; i < NQKV_; i += stride)
      biasqkv[i] = (i < E_) ? bq[i] : (i < 2*E_) ? bk[i - E_] : bv[i - 2*E_];
  } else {
    for (int i = t0; i < S_*64; i += stride) {
      int j = i & 63, s = i >> 6;
      float inv = exp2f(-(float)j * (13.287712379549449f / 64.0f)); // 10000^(-j/64)
      float ang = (float)s * inv;
      cosT[i] = cosf(ang);
      sinT[i] = sinf(ang);
    }
  }
}

// ================================================================ 8-phase 256^2 GEMM
// C = A * B^T + bias, bf16 out. 512 threads (8 waves 2Mx4N), BK=64, LDS 128KB.
// Pipelined frag ds_reads (issue one phase early, compiler-counted lgkmcnt),
// 1 barrier/phase, counted vmcnt(6) at group ends only.
#define STAGE8(basePtr, BUF, AB, KS, KT) do { \
    unsigned short* dst_ = lds + (BUF)*32768 + (AB)*16384 + (KS)*8192; \
    const unsigned short* src_ = (basePtr) + (KT)*64 + (KS)*32; \
    _Pragma("unroll") \
    for (int j_ = 0; j_ < 2; ++j_) { \
      int cc_ = (j_ << 9) + tid; \
      int row_ = cc_ >> 2, c2_ = cc_ & 3; \
      int sc_ = c2_ ^ ((row_ >> 1) & 3); \
      gload_lds16(src_ + (size_t)row_*K + sc_*8, (char*)dst_ + cc_*16); \
    } } while(0)

#define LOADA8(DST, MH, KS, BUF) do { \
    const unsigned short* Ab_ = lds + (BUF)*32768 + (KS)*8192; \
    _Pragma("unroll") \
    for (int j_ = 0; j_ < 4; ++j_) { \
      int row_ = wr*128 + ((MH)*4 + j_)*16 + l15; \
      DST[j_] = *(const bf16x8*)(Ab_ + row_*32 + ((l4 ^ ((row_>>1)&3)) << 3)); \
    } } while(0)

#define LOADB8(DST, KS, BUF) do { \
    const unsigned short* Bb_ = lds + (BUF)*32768 + 16384 + (KS)*8192; \
    _Pragma("unroll") \
    for (int j_ = 0; j_ < 4; ++j_) { \
      int row_ = wc*64 + j_*16 + l15; \
      DST[j_] = *(const bf16x8*)(Bb_ + row_*32 + ((l4 ^ ((row_>>1)&3)) << 3)); \
    } } while(0)

#define PRIO_MFMA(MH, AF, BF) do { \
    __builtin_amdgcn_s_setprio(1); \
    _Pragma("unroll") \
    for (int mm_ = 0; mm_ < 4; ++mm_) \
      _Pragma("unroll") \
      for (int nn_ = 0; nn_ < 4; ++nn_) \
        acc[(MH)*4+mm_][nn_] = __builtin_amdgcn_mfma_f32_16x16x32_bf16(AF[mm_], BF[nn_], acc[(MH)*4+mm_][nn_], 0,0,0); \
    __builtin_amdgcn_s_setprio(0); \
  } while(0)

#define BARPIN do { \
    __builtin_amdgcn_sched_barrier(0); \
    __builtin_amdgcn_s_barrier(); \
    __builtin_amdgcn_sched_barrier(0); \
  } while(0)

__global__ __launch_bounds__(512, 2) void gemm8(
    const unsigned short* __restrict__ A,
    const unsigned short* __restrict__ Bm,
    const float* __restrict__ bias,
    unsigned short* __restrict__ Cv,
    int M, int N, int K)
{
  __shared__ __align__(16) unsigned short lds[65536];   // 128 KB
  const int tid = threadIdx.x;
  const int lane = tid & 63;
  const int w = tid >> 6;             // 0..7
  const int wr = w >> 2, wc = w & 3;  // 2 x 4
  const int l15 = lane & 15, l4 = lane >> 4;

  const int ntile = N >> 8;
  int wg = blockIdx.x;
  const int cpx = gridDim.x >> 3;     // grid % 8 == 0 for our shapes
  wg = (wg & 7) * cpx + (wg >> 3);
  const int tm = wg / ntile, tn = wg % ntile;

  const unsigned short* Abase = A + ((size_t)tm*256)*K;
  const unsigned short* Bbase = Bm + ((size_t)tn*256)*K;

  f32x4 acc[8][4] = {};
  bf16x8 afA[4], afB[4], bfA[4], bfB[4];

  const int NITER = K >> 7;   // 2 K-tiles (BK=64) per iteration

  // Prologue: t0's 4 halves + t1's first 3 halves, retire t0 fully.
  STAGE8(Bbase, 0, 1, 0, 0); STAGE8(Abase, 0, 0, 0, 0);
  STAGE8(Bbase, 0, 1, 1, 0); STAGE8(Abase, 0, 0, 1, 0);
  STAGE8(Bbase, 1, 1, 0, 1); STAGE8(Abase, 1, 0, 0, 1);
  STAGE8(Bbase, 1, 1, 1, 1);
  __builtin_amdgcn_sched_barrier(0);
  asm volatile("s_waitcnt vmcnt(6)" ::: "memory");
  __builtin_amdgcn_s_barrier();
  __builtin_amdgcn_sched_barrier(0);

  for (int i = 0; i < NITER; ++i) {
    const int t1k = 2*i + 1, t2k = 2*i + 2, t3k = 2*i + 3;
    const bool nl = (i < NITER - 1);
    // ---------------- group 1: buf0 (tile 2i)
    STAGE8(Abase, 1, 0, 1, t1k);                 // s1: buf1 ks1 (readers done prev iter)
    LOADA8(afA, 0, 0, 0); LOADB8(bfA, 0, 0);     // R1 (Q1 frags)
    LOADA8(afB, 1, 0, 0);                        // R2
    PRIO_MFMA(0, afA, bfA);                      // Q1 (waits R1)
    BARPIN;                                      // all R1 done
    if (nl) STAGE8(Bbase, 0, 1, 0, t2k);         // s2: overwrites B0ks0 (read in R1)
    LOADA8(afA, 0, 1, 0); LOADB8(bfB, 1, 0);     // R3
    PRIO_MFMA(1, afB, bfA);                      // Q2 (waits R2)
    BARPIN;                                      // all R2 done
    if (nl) STAGE8(Abase, 0, 0, 0, t2k);         // s3: overwrites A0ks0 (read R1+R2)
    LOADA8(afB, 1, 1, 0);                        // R4
    PRIO_MFMA(0, afA, bfB);                      // Q3 (waits R3)
    BARPIN;                                      // all R3 done
    if (nl) STAGE8(Bbase, 0, 1, 1, t2k);         // s4: overwrites B0ks1 (read in R3)
    PRIO_MFMA(1, afB, bfB);                      // Q4 (waits R4)
    __builtin_amdgcn_sched_barrier(0);
    if (nl) asm volatile("s_waitcnt vmcnt(6)" ::: "memory");
    else    asm volatile("s_waitcnt vmcnt(0)" ::: "memory");
    __builtin_amdgcn_s_barrier();
    __builtin_amdgcn_sched_barrier(0);
    // ---------------- group 2: buf1 (tile 2i+1)
    if (nl) STAGE8(Abase, 0, 0, 1, t2k);         // s1': buf0 ks1 (readers done group1)
    LOADA8(afA, 0, 0, 1); LOADB8(bfA, 0, 1);     // R1
    LOADA8(afB, 1, 0, 1);                        // R2
    PRIO_MFMA(0, afA, bfA);                      // Q1
    BARPIN;
    if (nl) STAGE8(Bbase, 1, 1, 0, t3k);         // s2'
    LOADA8(afA, 0, 1, 1); LOADB8(bfB, 1, 1);     // R3
    PRIO_MFMA(1, afB, bfA);                      // Q2
    BARPIN;
    if (nl) STAGE8(Abase, 1, 0, 0, t3k);         // s3'
    LOADA8(afB, 1, 1, 1);                        // R4
    PRIO_MFMA(0, afA, bfB);                      // Q3
    BARPIN;
    if (nl) STAGE8(Bbase, 1, 1, 1, t3k);         // s4'
    PRIO_MFMA(1, afB, bfB);                      // Q4
    __builtin_amdgcn_sched_barrier(0);
    if (nl) asm volatile("s_waitcnt vmcnt(6)" ::: "memory");
    else    asm volatile("s_waitcnt vmcnt(0)" ::: "memory");
    __builtin_amdgcn_s_barrier();
    __builtin_amdgcn_sched_barrier(0);
  }

  #pragma unroll
  for (int mt = 0; mt < 8; ++mt) {
    #pragma unroll
    for (int nt = 0; nt < 4; ++nt) {
      int colg = tn*256 + wc*64 + nt*16 + l15;
      float bvv = bias[colg];
      #pragma unroll
      for (int r = 0; r < 4; ++r) {
        int rowg = tm*256 + wr*128 + mt*16 + l4*4 + r;
        Cv[(size_t)rowg*N + colg] = f2bf(acc[mt][nt][r] + bvv);
      }
    }
  }
}

// ------------------------------------------------- GEMM  C = A * B^T + bias (128^2, known-good)
template<int OUT_F32>
__global__ __launch_bounds__(256) void gemm_bt(
    const unsigned short* __restrict__ A,
    const unsigned short* __restrict__ Bm,
    const float* __restrict__ bias,
    void* __restrict__ Cv,
    int M, int N, int K)
{
  __shared__ unsigned short lA[128*64];
  __shared__ unsigned short lB[128*64];
  const int tid = threadIdx.x;
  const int lane = tid & 63;
  const int w = tid >> 6;
  const int wr = w >> 1, wc = w & 1;
  const int ntile = N >> 7;
  const int tm = blockIdx.x / ntile, tn = blockIdx.x % ntile;
  const int l15 = lane & 15, l4 = lane >> 4;

  f32x4 acc[4][4] = {};

  for (int kt = 0; kt < K; kt += 64) {
    #pragma unroll
    for (int i = 0; i < 4; ++i) {
      int cc = i*256 + tid;
      int row = cc >> 3, col = cc & 7;
      int scol = col ^ (row & 7);
      gload_lds16(A + (size_t)(tm*128 + row)*K + kt + scol*8, (char*)lA + cc*16);
    }
    #pragma unroll
    for (int i = 0; i < 4; ++i) {
      int cc = i*256 + tid;
      int row = cc >> 3, col = cc & 7;
      int scol = col ^ (row & 7);
      gload_lds16(Bm + (size_t)(tn*128 + row)*K + kt + scol*8, (char*)lB + cc*16);
    }
    asm volatile("s_waitcnt vmcnt(0)" ::: "memory");
    __syncthreads();

    #pragma unroll
    for (int ks = 0; ks < 2; ++ks) {
      bf16x8 af[4], bfr[4];
      #pragma unroll
      for (int mt = 0; mt < 4; ++mt) {
        int row = wr*64 + mt*16 + l15;
        int ch = (ks*4 + l4) ^ (row & 7);
        af[mt] = *(const bf16x8*)(lA + row*64 + ch*8);
      }
      #pragma unroll
      for (int nt = 0; nt < 4; ++nt) {
        int row = wc*64 + nt*16 + l15;
        int ch = (ks*4 + l4) ^ (row & 7);
        bfr[nt] = *(const bf16x8*)(lB + row*64 + ch*8);
      }
      #pragma unroll
      for (int mt = 0; mt < 4; ++mt)
        #pragma unroll
        for (int nt = 0; nt < 4; ++nt)
          acc[mt][nt] = __builtin_amdgcn_mfma_f32_16x16x32_bf16(af[mt], bfr[nt], acc[mt][nt], 0, 0, 0);
    }
    __syncthreads();
  }

  #pragma unroll
  for (int mt = 0; mt < 4; ++mt) {
    #pragma unroll
    for (int nt = 0; nt < 4; ++nt) {
      int colg = tn*128 + wc*64 + nt*16 + l15;
      float bvv = bias[colg];
      #pragma unroll
      for (int r = 0; r < 4; ++r) {
        int rowg = tm*128 + wr*64 + mt*16 + l4*4 + r;
        float v = acc[mt][nt][r] + bvv;
        if (OUT_F32) ((float*)Cv)[(size_t)rowg*N + colg] = v;
        else ((unsigned short*)Cv)[(size_t)rowg*N + colg] = f2bf(v);
      }
    }
  }
}

// ---------------------------------------------------------------- RoPE (in-place on qkv)
// q additionally scaled by log2(e)/sqrt(D) so attention works in exp2 domain.
__global__ __launch_bounds__(256) void rope_kernel(
    unsigned short* __restrict__ qkv, const float* __restrict__ cosT, const float* __restrict__ sinT)
{
  int t = blockIdx.x*256 + threadIdx.x;            // M_*H_*64 threads
  int i  = t & 63;
  int h  = (t >> 6) & 15;
  int m  = t >> 10;
  int s  = m & (S_-1);
  float c = cosT[s*64 + i], sn = sinT[s*64 + i];
  const float scale = 0.08838834764831845f * 1.4426950408889634f; // log2e/sqrt(128)
  size_t base = (size_t)m*NQKV_ + h*128;
  float q1 = bf2f(qkv[base+i]), q2 = bf2f(qkv[base+64+i]);
  qkv[base+i]    = f2bf((q1*c - q2*sn)*scale);
  qkv[base+64+i] = f2bf((q2*c + q1*sn)*scale);
  size_t kb = base + E_;
  float k1 = bf2f(qkv[kb+i]), k2 = bf2f(qkv[kb+64+i]);
  qkv[kb+i]    = f2bf(k1*c - k2*sn);
  qkv[kb+64+i] = f2bf(k2*c + k1*sn);
}

// ---------------------------------------------------------------- V transpose -> [B,H,D,S]
__global__ __launch_bounds__(256) void transv_kernel(
    const unsigned short* __restrict__ qkv, unsigned short* __restrict__ Vt)
{
  __shared__ unsigned short t[32][33];
  int bid = blockIdx.x;
  int st = bid & 63;
  int dt = (bid >> 6) & 3;
  int bh = bid >> 8;
  int b = bh >> 4, h = bh & 15;
  int tx = threadIdx.x & 31, ty = threadIdx.x >> 5;
  #pragma unroll
  for (int j = 0; j < 4; ++j) {
    int r = ty + j*8;
    t[r][tx] = qkv[(size_t)(b*S_ + st*32 + r)*NQKV_ + 2*E_ + h*128 + dt*32 + tx];
  }
  __syncthreads();
  #pragma unroll
  for (int j = 0; j < 4; ++j) {
    int r = ty + j*8;
    Vt[((size_t)bh*D_ + dt*32 + r)*S_ + st*32 + tx] = t[tx][r];
  }
}

// ---------------------------------------------------------------- flash attention
__global__ __launch_bounds__(256, 4) void attn_kernel(
    const unsigned short* __restrict__ qkv, const unsigned short* __restrict__ Vt,
    unsigned short* __restrict__ Ao)
{
  __shared__ unsigned short lK[64*128];                 // 16 KB
  __shared__ unsigned short lV[128*64];                 // 16 KB
  __shared__ __align__(16) unsigned short lP[4*16*64];  // 8 KB (bf16 P per wave)
  const int bid = blockIdx.x;
  const int qt = bid & 31;
  const int bh = bid >> 5;
  const int b = bh >> 4, h = bh & 15;
  const int tid = threadIdx.x, lane = tid & 63, w = tid >> 6;
  const int l15 = lane & 15, l4 = lane >> 4;

  const int qrow = qt*64 + w*16 + l15;
  const unsigned short* qp = qkv + (size_t)(b*S_ + qrow)*NQKV_ + h*128 + l4*8;
  bf16x8 qf[4];
  #pragma unroll
  for (int f = 0; f < 4; ++f) qf[f] = *(const bf16x8*)(qp + f*32);

  f32x4 O[8];
  #pragma unroll
  for (int i = 0; i < 8; ++i) O[i] = (f32x4){0.f,0.f,0.f,0.f};
  float m = -1e30f, lsum = 0.f;

  unsigned short* myP = lP + w*(16*64);
  const int ksw = (l15 & 7) << 3;
  const size_t kbase = (size_t)b*S_*NQKV_ + E_ + (size_t)h*128;
  const size_t vbase = (size_t)bh*D_*S_;

  for (int kt = 0; kt < S_; kt += 64) {
    #pragma unroll
    for (int i = 0; i < 4; ++i) {
      int cc = i*256 + tid;
      int row = cc >> 4, col = cc & 15;
      int scol = col ^ (row & 7);
      gload_lds16(qkv + kbase + (size_t)(kt + row)*NQKV_ + scol*8, (char*)lK + cc*16);
    }
    #pragma unroll
    for (int i = 0; i < 4; ++i) {
      int cc = i*256 + tid;
      int row = cc >> 3, col = cc & 7;
      int scol = col ^ ((row & 7) ^ ((row >> 3) & 7));
      gload_lds16(Vt + vbase + (size_t)row*S_ + kt + scol*8, (char*)lV + cc*16);
    }
    asm volatile("s_waitcnt vmcnt(0)" ::: "memory");
    __syncthreads();

    // S^T = K Q^T : sfr[nf][r] = S[key = kt + nf*16 + l4*4 + r][q = l15]
    f32x4 sfr[4];
    #pragma unroll
    for (int nf = 0; nf < 4; ++nf) {
      f32x4 s = (f32x4){0.f,0.f,0.f,0.f};
      #pragma unroll
      for (int ks = 0; ks < 4; ++ks) {
        int row = nf*16 + l15;
        int ch = (ks*4 + l4) ^ (row & 7);
        bf16x8 kf = *(const bf16x8*)(lK + row*128 + ch*8);
        s = __builtin_amdgcn_mfma_f32_16x16x32_bf16(kf, qf[ks], s, 0, 0, 0);
      }
      sfr[nf] = s;
    }

    float vmax = -1e30f;
    #pragma unroll
    for (int nf = 0; nf < 4; ++nf)
      #pragma unroll
      for (int r = 0; r < 4; ++r) vmax = fmaxf(vmax, sfr[nf][r]);
    vmax = fmaxf(vmax, __shfl_xor(vmax, 16, 64));
    vmax = fmaxf(vmax, __shfl_xor(vmax, 32, 64));

    if (__any(vmax > m + 8.0f)) {
      float mn = fmaxf(m, vmax);
      float al = __builtin_amdgcn_exp2f(m - mn);
      m = mn;
      lsum *= al;
      #pragma unroll
      for (int r = 0; r < 4; ++r) {
        float ar = __shfl(al, (lane & 48) + l4*4 + r, 64);
        #pragma unroll
        for (int df = 0; df < 8; ++df) O[df][r] *= ar;
      }
    }

    float ps = 0.f;
    #pragma unroll
    for (int nf = 0; nf < 4; ++nf) {
      #pragma unroll
      for (int r = 0; r < 4; ++r) {
        float p = __builtin_amdgcn_exp2f(sfr[nf][r] - m);
        sfr[nf][r] = p;
        ps += p;
      }
    }
    ps += __shfl_xor(ps, 16, 64);
    ps += __shfl_xor(ps, 32, 64);
    lsum += ps;

    #pragma unroll
    for (int nf = 0; nf < 4; ++nf) {
      unsigned lo = (unsigned)f2bf(sfr[nf][0]) | ((unsigned)f2bf(sfr[nf][1]) << 16);
      unsigned hi = (unsigned)f2bf(sfr[nf][2]) | ((unsigned)f2bf(sfr[nf][3]) << 16);
      int k0 = (nf*16 + l4*4) ^ ksw;
      u32x2 val; val[0] = lo; val[1] = hi;
      *(u32x2*)(myP + l15*64 + k0) = val;
    }
    asm volatile("s_waitcnt lgkmcnt(0)" ::: "memory");

    #pragma unroll
    for (int ks2 = 0; ks2 < 2; ++ks2) {
      int kk = (ks2*32 + l4*8) ^ ksw;
      bf16x8 pf = *(const bf16x8*)(myP + l15*64 + kk);
      #pragma unroll
      for (int df = 0; df < 8; ++df) {
        int row = df*16 + l15;
        int ch = (ks2*4 + l4) ^ ((row & 7) ^ ((row >> 3) & 7));
        bf16x8 vf = *(const bf16x8*)(lV + row*64 + ch*8);
        O[df] = __builtin_amdgcn_mfma_f32_16x16x32_bf16(pf, vf, O[df], 0, 0, 0);
      }
    }
    __syncthreads();
  }

  float linv = 1.0f / lsum;
  float inv[4];
  #pragma unroll
  for (int r = 0; r < 4; ++r) inv[r] = __shfl(linv, (lane & 48) + l4*4 + r, 64);
  #pragma unroll
  for (int df = 0; df < 8; ++df) {
    int colg = h*128 + df*16 + l15;
    #pragma unroll
    for (int r = 0; r < 4; ++r) {
      int rowg = qt*64 + w*16 + l4*4 + r;
      Ao[(size_t)(b*S_ + rowg)*E_ + colg] = f2bf(O[df][r] * inv[r]);
    }
  }
}

// ----------------------------------------------------------------
extern "C" void kernel_launch(void* const* d_in, const int* in_sizes, int n_in,
                              void* d_out, int out_size, void* d_ws, size_t ws_size,
                              hipStream_t stream) {
  const float* hs = (const float*)d_in[0];
  const float* Wq = (const float*)d_in[1];
  const float* bq = (const float*)d_in[2];
  const float* Wk = (const float*)d_in[3];
  const float* bk = (const float*)d_in[4];
  const float* Wv = (const float*)d_in[5];
  const float* bv = (const float*)d_in[6];
  const float* Wo = (const float*)d_in[7];
  const float* bo = (const float*)d_in[8];
  float* out = (float*)d_out;

  char* p = (char*)d_ws;
  auto alloc = [&](size_t bytes) { char* r = p; p += (bytes + 255) & ~(size_t)255; return r; };
  unsigned short* hsb  = (unsigned short*)alloc((size_t)M_*E_*2);
  unsigned short* Wqkv = (unsigned short*)alloc((size_t)NQKV_*E_*2);
  unsigned short* Wob  = (unsigned short*)alloc((size_t)E_*E_*2);
  unsigned short* qkv  = (unsigned short*)alloc((size_t)M_*NQKV_*2);
  unsigned short* Vt   = (unsigned short*)alloc((size_t)B_*H_*D_*S_*2);
  unsigned short* Ao   = (unsigned short*)alloc((size_t)M_*E_*2);
  float* biasqkv = (float*)alloc((size_t)NQKV_*4);
  float* cosT = (float*)alloc((size_t)S_*64*4);
  float* sinT = (float*)alloc((size_t)S_*64*4);

  prep_kernel<<<dim3(2048, 5), 256, 0, stream>>>(hs, Wq, Wk, Wv, Wo, bq, bk, bv,
      hsb, Wqkv, Wob, biasqkv, cosT, sinT);
  gemm8<<<dim3((M_/256)*(NQKV_/256)), 512, 0, stream>>>(hsb, Wqkv, biasqkv, qkv, M_, NQKV_, E_);
  rope_kernel<<<dim3((M_*H_*64)/256), 256, 0, stream>>>(qkv, cosT, sinT);
  transv_kernel<<<dim3(B_*H_*(D_/32)*(S_/32)), 256, 0, stream>>>(qkv, Vt);
  attn_kernel<<<dim3(B_*H_*(S_/64)), 256, 0, stream>>>(qkv, Vt, Ao);
  gemm_bt<1><<<dim3((M_/128)*(E_/128)), 256, 0, stream>>>(Ao, Wob, bo, out, M_, E_, E_);
}

// Round 6
// 295.963 us; speedup vs baseline: 1.2295x; 1.0748x over previous
//
#include <hip/hip_runtime.h>
#include <hip/hip_bf16.h>

#define B_ 2
#define S_ 2048
#define E_ 2048
#define H_ 16
#define D_ 128
#define M_ (B_*S_)
#define NQKV_ (3*E_)

typedef __attribute__((ext_vector_type(8))) short bf16x8;
typedef __attribute__((ext_vector_type(4))) float f32x4;
typedef __attribute__((ext_vector_type(4))) unsigned short u16x4;
typedef __attribute__((ext_vector_type(2))) unsigned u32x2;

__device__ __forceinline__ unsigned short f2bf(float f) {
  union { float f; unsigned u; } v; v.f = f;
  unsigned r = v.u + 0x7fffu + ((v.u >> 16) & 1u);
  return (unsigned short)(r >> 16);
}
__device__ __forceinline__ float bf2f(unsigned short h) {
  union { unsigned u; float f; } v; v.u = ((unsigned)h) << 16;
  return v.f;
}

__device__ __forceinline__ void gload_lds16(const void* g, void* l) {
  __builtin_amdgcn_global_load_lds(
      (const __attribute__((address_space(1))) unsigned*)g,
      (__attribute__((address_space(3))) unsigned*)l, 16, 0, 0);
}

// ---------------------------------------------------------------- prep
__global__ __launch_bounds__(256) void prep_kernel(
    const float* __restrict__ hs,
    const float* __restrict__ Wq, const float* __restrict__ Wk, const float* __restrict__ Wv,
    const float* __restrict__ Wo,
    const float* __restrict__ bq, const float* __restrict__ bk, const float* __restrict__ bv,
    unsigned short* __restrict__ hsb, unsigned short* __restrict__ Wqkv,
    unsigned short* __restrict__ Wob, float* __restrict__ biasqkv,
    float* __restrict__ cosT, float* __restrict__ sinT)
{
  const int seg = blockIdx.y;
  const int t0 = blockIdx.x * 256 + threadIdx.x;
  const int stride = gridDim.x * 256;
  if (seg == 0) {
    const int n = (M_*E_)/4;
    for (int i = t0; i < n; i += stride) {
      f32x4 v = ((const f32x4*)hs)[i];
      u16x4 o; o[0]=f2bf(v[0]); o[1]=f2bf(v[1]); o[2]=f2bf(v[2]); o[3]=f2bf(v[3]);
      ((u16x4*)hsb)[i] = o;
    }
  } else if (seg == 1) {
    const int n = (3*E_*E_)/4;
    for (int i = t0; i < n; i += stride) {
      int e4 = i << 2;
      int r = e4 >> 11;
      int k = e4 & 2047;
      const float* src = (r < E_) ? (Wq + ((size_t)r << 11) + k)
                       : (r < 2*E_) ? (Wk + ((size_t)(r - E_) << 11) + k)
                       : (Wv + ((size_t)(r - 2*E_) << 11) + k);
      f32x4 v = *(const f32x4*)src;
      u16x4 o; o[0]=f2bf(v[0]); o[1]=f2bf(v[1]); o[2]=f2bf(v[2]); o[3]=f2bf(v[3]);
      ((u16x4*)Wqkv)[i] = o;
    }
  } else if (seg == 2) {
    const int n = (E_*E_)/4;
    for (int i = t0; i < n; i += stride) {
      f32x4 v = ((const f32x4*)Wo)[i];
      u16x4 o; o[0]=f2bf(v[0]); o[1]=f2bf(v[1]); o[2]=f2bf(v[2]); o[3]=f2bf(v[3]);
      ((u16x4*)Wob)[i] = o;
    }
  } else if (seg == 3) {
    for (int i = t0; i < NQKV_; i += stride)
      biasqkv[i] = (i < E_) ? bq[i] : (i < 2*E_) ? bk[i - E_] : bv[i - 2*E_];
  } else {
    for (int i = t0; i < S_*64; i += stride) {
      int j = i & 63, s = i >> 6;
      float inv = exp2f(-(float)j * (13.287712379549449f / 64.0f)); // 10000^(-j/64)
      float ang = (float)s * inv;
      cosT[i] = cosf(ang);
      sinT[i] = sinf(ang);
    }
  }
}

// ================================================================ 8-phase 256^2 GEMM
#define STAGE8(basePtr, BUF, AB, KS, KT) do { \
    unsigned short* dst_ = lds + (BUF)*32768 + (AB)*16384 + (KS)*8192; \
    const unsigned short* src_ = (basePtr) + (KT)*64 + (KS)*32; \
    _Pragma("unroll") \
    for (int j_ = 0; j_ < 2; ++j_) { \
      int cc_ = (j_ << 9) + tid; \
      int row_ = cc_ >> 2, c2_ = cc_ & 3; \
      int sc_ = c2_ ^ ((row_ >> 1) & 3); \
      gload_lds16(src_ + (size_t)row_*K + sc_*8, (char*)dst_ + cc_*16); \
    } } while(0)

#define LOADA8(DST, MH, KS, BUF) do { \
    const unsigned short* Ab_ = lds + (BUF)*32768 + (KS)*8192; \
    _Pragma("unroll") \
    for (int j_ = 0; j_ < 4; ++j_) { \
      int row_ = wr*128 + ((MH)*4 + j_)*16 + l15; \
      DST[j_] = *(const bf16x8*)(Ab_ + row_*32 + ((l4 ^ ((row_>>1)&3)) << 3)); \
    } } while(0)

#define LOADB8(DST, KS, BUF) do { \
    const unsigned short* Bb_ = lds + (BUF)*32768 + 16384 + (KS)*8192; \
    _Pragma("unroll") \
    for (int j_ = 0; j_ < 4; ++j_) { \
      int row_ = wc*64 + j_*16 + l15; \
      DST[j_] = *(const bf16x8*)(Bb_ + row_*32 + ((l4 ^ ((row_>>1)&3)) << 3)); \
    } } while(0)

#define PRIO_MFMA(MH, AF, BF) do { \
    __builtin_amdgcn_s_setprio(1); \
    _Pragma("unroll") \
    for (int mm_ = 0; mm_ < 4; ++mm_) \
      _Pragma("unroll") \
      for (int nn_ = 0; nn_ < 4; ++nn_) \
        acc[(MH)*4+mm_][nn_] = __builtin_amdgcn_mfma_f32_16x16x32_bf16(AF[mm_], BF[nn_], acc[(MH)*4+mm_][nn_], 0,0,0); \
    __builtin_amdgcn_s_setprio(0); \
  } while(0)

#define BARPIN do { \
    __builtin_amdgcn_sched_barrier(0); \
    __builtin_amdgcn_s_barrier(); \
    __builtin_amdgcn_sched_barrier(0); \
  } while(0)

__global__ __launch_bounds__(512, 2) void gemm8(
    const unsigned short* __restrict__ A,
    const unsigned short* __restrict__ Bm,
    const float* __restrict__ bias,
    unsigned short* __restrict__ Cv,
    int M, int N, int K)
{
  __shared__ __align__(16) unsigned short lds[65536];   // 128 KB
  const int tid = threadIdx.x;
  const int lane = tid & 63;
  const int w = tid >> 6;             // 0..7
  const int wr = w >> 2, wc = w & 3;  // 2 x 4
  const int l15 = lane & 15, l4 = lane >> 4;

  const int ntile = N >> 8;
  int wg = blockIdx.x;
  const int cpx = gridDim.x >> 3;     // grid % 8 == 0 for our shapes
  wg = (wg & 7) * cpx + (wg >> 3);
  const int tm = wg / ntile, tn = wg % ntile;

  const unsigned short* Abase = A + ((size_t)tm*256)*K;
  const unsigned short* Bbase = Bm + ((size_t)tn*256)*K;

  f32x4 acc[8][4] = {};
  bf16x8 afA[4], afB[4], bfA[4], bfB[4];

  const int NITER = K >> 7;   // 2 K-tiles (BK=64) per iteration

  STAGE8(Bbase, 0, 1, 0, 0); STAGE8(Abase, 0, 0, 0, 0);
  STAGE8(Bbase, 0, 1, 1, 0); STAGE8(Abase, 0, 0, 1, 0);
  STAGE8(Bbase, 1, 1, 0, 1); STAGE8(Abase, 1, 0, 0, 1);
  STAGE8(Bbase, 1, 1, 1, 1);
  __builtin_amdgcn_sched_barrier(0);
  asm volatile("s_waitcnt vmcnt(6)" ::: "memory");
  __builtin_amdgcn_s_barrier();
  __builtin_amdgcn_sched_barrier(0);

  for (int i = 0; i < NITER; ++i) {
    const int t1k = 2*i + 1, t2k = 2*i + 2, t3k = 2*i + 3;
    const bool nl = (i < NITER - 1);
    // ---------------- group 1: buf0 (tile 2i)
    STAGE8(Abase, 1, 0, 1, t1k);
    LOADA8(afA, 0, 0, 0); LOADB8(bfA, 0, 0);
    LOADA8(afB, 1, 0, 0);
    PRIO_MFMA(0, afA, bfA);
    BARPIN;
    if (nl) STAGE8(Bbase, 0, 1, 0, t2k);
    LOADA8(afA, 0, 1, 0); LOADB8(bfB, 1, 0);
    PRIO_MFMA(1, afB, bfA);
    BARPIN;
    if (nl) STAGE8(Abase, 0, 0, 0, t2k);
    LOADA8(afB, 1, 1, 0);
    PRIO_MFMA(0, afA, bfB);
    BARPIN;
    if (nl) STAGE8(Bbase, 0, 1, 1, t2k);
    PRIO_MFMA(1, afB, bfB);
    __builtin_amdgcn_sched_barrier(0);
    if (nl) asm volatile("s_waitcnt vmcnt(6)" ::: "memory");
    else    asm volatile("s_waitcnt vmcnt(0)" ::: "memory");
    __builtin_amdgcn_s_barrier();
    __builtin_amdgcn_sched_barrier(0);
    // ---------------- group 2: buf1 (tile 2i+1)
    if (nl) STAGE8(Abase, 0, 0, 1, t2k);
    LOADA8(afA, 0, 0, 1); LOADB8(bfA, 0, 1);
    LOADA8(afB, 1, 0, 1);
    PRIO_MFMA(0, afA, bfA);
    BARPIN;
    if (nl) STAGE8(Bbase, 1, 1, 0, t3k);
    LOADA8(afA, 0, 1, 1); LOADB8(bfB, 1, 1);
    PRIO_MFMA(1, afB, bfA);
    BARPIN;
    if (nl) STAGE8(Abase, 1, 0, 0, t3k);
    LOADA8(afB, 1, 1, 1);
    PRIO_MFMA(0, afA, bfB);
    BARPIN;
    if (nl) STAGE8(Bbase, 1, 1, 1, t3k);
    PRIO_MFMA(1, afB, bfB);
    __builtin_amdgcn_sched_barrier(0);
    if (nl) asm volatile("s_waitcnt vmcnt(6)" ::: "memory");
    else    asm volatile("s_waitcnt vmcnt(0)" ::: "memory");
    __builtin_amdgcn_s_barrier();
    __builtin_amdgcn_sched_barrier(0);
  }

  #pragma unroll
  for (int mt = 0; mt < 8; ++mt) {
    #pragma unroll
    for (int nt = 0; nt < 4; ++nt) {
      int colg = tn*256 + wc*64 + nt*16 + l15;
      float bvv = bias[colg];
      #pragma unroll
      for (int r = 0; r < 4; ++r) {
        int rowg = tm*256 + wr*128 + mt*16 + l4*4 + r;
        Cv[(size_t)rowg*N + colg] = f2bf(acc[mt][nt][r] + bvv);
      }
    }
  }
}

// ------------------------------------------------- GEMM  C = A * B^T + bias (128^2, known-good)
template<int OUT_F32>
__global__ __launch_bounds__(256) void gemm_bt(
    const unsigned short* __restrict__ A,
    const unsigned short* __restrict__ Bm,
    const float* __restrict__ bias,
    void* __restrict__ Cv,
    int M, int N, int K)
{
  __shared__ unsigned short lA[128*64];
  __shared__ unsigned short lB[128*64];
  const int tid = threadIdx.x;
  const int lane = tid & 63;
  const int w = tid >> 6;
  const int wr = w >> 1, wc = w & 1;
  const int ntile = N >> 7;
  const int tm = blockIdx.x / ntile, tn = blockIdx.x % ntile;
  const int l15 = lane & 15, l4 = lane >> 4;

  f32x4 acc[4][4] = {};

  for (int kt = 0; kt < K; kt += 64) {
    #pragma unroll
    for (int i = 0; i < 4; ++i) {
      int cc = i*256 + tid;
      int row = cc >> 3, col = cc & 7;
      int scol = col ^ (row & 7);
      gload_lds16(A + (size_t)(tm*128 + row)*K + kt + scol*8, (char*)lA + cc*16);
    }
    #pragma unroll
    for (int i = 0; i < 4; ++i) {
      int cc = i*256 + tid;
      int row = cc >> 3, col = cc & 7;
      int scol = col ^ (row & 7);
      gload_lds16(Bm + (size_t)(tn*128 + row)*K + kt + scol*8, (char*)lB + cc*16);
    }
    asm volatile("s_waitcnt vmcnt(0)" ::: "memory");
    __syncthreads();

    #pragma unroll
    for (int ks = 0; ks < 2; ++ks) {
      bf16x8 af[4], bfr[4];
      #pragma unroll
      for (int mt = 0; mt < 4; ++mt) {
        int row = wr*64 + mt*16 + l15;
        int ch = (ks*4 + l4) ^ (row & 7);
        af[mt] = *(const bf16x8*)(lA + row*64 + ch*8);
      }
      #pragma unroll
      for (int nt = 0; nt < 4; ++nt) {
        int row = wc*64 + nt*16 + l15;
        int ch = (ks*4 + l4) ^ (row & 7);
        bfr[nt] = *(const bf16x8*)(lB + row*64 + ch*8);
      }
      #pragma unroll
      for (int mt = 0; mt < 4; ++mt)
        #pragma unroll
        for (int nt = 0; nt < 4; ++nt)
          acc[mt][nt] = __builtin_amdgcn_mfma_f32_16x16x32_bf16(af[mt], bfr[nt], acc[mt][nt], 0, 0, 0);
    }
    __syncthreads();
  }

  #pragma unroll
  for (int mt = 0; mt < 4; ++mt) {
    #pragma unroll
    for (int nt = 0; nt < 4; ++nt) {
      int colg = tn*128 + wc*64 + nt*16 + l15;
      float bvv = bias[colg];
      #pragma unroll
      for (int r = 0; r < 4; ++r) {
        int rowg = tm*128 + wr*64 + mt*16 + l4*4 + r;
        float v = acc[mt][nt][r] + bvv;
        if (OUT_F32) ((float*)Cv)[(size_t)rowg*N + colg] = v;
        else ((unsigned short*)Cv)[(size_t)rowg*N + colg] = f2bf(v);
      }
    }
  }
}

// ---------------------------------------------------------------- RoPE (in-place on qkv)
__global__ __launch_bounds__(256) void rope_kernel(
    unsigned short* __restrict__ qkv, const float* __restrict__ cosT, const float* __restrict__ sinT)
{
  int t = blockIdx.x*256 + threadIdx.x;            // M_*H_*64 threads
  int i  = t & 63;
  int h  = (t >> 6) & 15;
  int m  = t >> 10;
  int s  = m & (S_-1);
  float c = cosT[s*64 + i], sn = sinT[s*64 + i];
  const float scale = 0.08838834764831845f * 1.4426950408889634f; // log2e/sqrt(128)
  size_t base = (size_t)m*NQKV_ + h*128;
  float q1 = bf2f(qkv[base+i]), q2 = bf2f(qkv[base+64+i]);
  qkv[base+i]    = f2bf((q1*c - q2*sn)*scale);
  qkv[base+64+i] = f2bf((q2*c + q1*sn)*scale);
  size_t kb = base + E_;
  float k1 = bf2f(qkv[kb+i]), k2 = bf2f(qkv[kb+64+i]);
  qkv[kb+i]    = f2bf(k1*c - k2*sn);
  qkv[kb+64+i] = f2bf(k2*c + k1*sn);
}

// ---------------------------------------------------------------- V transpose -> [B,H,D,S]
__global__ __launch_bounds__(256) void transv_kernel(
    const unsigned short* __restrict__ qkv, unsigned short* __restrict__ Vt)
{
  __shared__ unsigned short t[32][33];
  int bid = blockIdx.x;
  int st = bid & 63;
  int dt = (bid >> 6) & 3;
  int bh = bid >> 8;
  int b = bh >> 4, h = bh & 15;
  int tx = threadIdx.x & 31, ty = threadIdx.x >> 5;
  #pragma unroll
  for (int j = 0; j < 4; ++j) {
    int r = ty + j*8;
    t[r][tx] = qkv[(size_t)(b*S_ + st*32 + r)*NQKV_ + 2*E_ + h*128 + dt*32 + tx];
  }
  __syncthreads();
  #pragma unroll
  for (int j = 0; j < 4; ++j) {
    int r = ty + j*8;
    Vt[((size_t)bh*D_ + dt*32 + r)*S_ + st*32 + tx] = t[tx][r];
  }
}

// ---------------------------------------------------------------- flash attention
// 128 q-rows/block (4 waves x 32 q). Each K/V LDS fragment read feeds 2 MFMAs
// (two q-groups) -> LDS-read bytes per MFMA halved vs 16q/wave version.
__global__ __launch_bounds__(256, 2) void attn_kernel(
    const unsigned short* __restrict__ qkv, const unsigned short* __restrict__ Vt,
    unsigned short* __restrict__ Ao)
{
  __shared__ unsigned short lK[64*128];                 // 16 KB
  __shared__ unsigned short lV[128*64];                 // 16 KB
  __shared__ __align__(16) unsigned short lP[4*32*64];  // 16 KB (bf16 P per wave)
  int bid = blockIdx.x;
  bid = (bid & 7)*64 + (bid >> 3);     // chunked XCD swizzle (512 = 8*64)
  const int qt = bid & 15;
  const int bh = bid >> 4;
  const int b = bh >> 4, h = bh & 15;
  const int tid = threadIdx.x, lane = tid & 63, w = tid >> 6;
  const int l15 = lane & 15, l4 = lane >> 4;

  bf16x8 qf[2][4];
  #pragma unroll
  for (int g = 0; g < 2; ++g) {
    const int qrow = qt*128 + w*32 + g*16 + l15;
    const unsigned short* qp = qkv + (size_t)(b*S_ + qrow)*NQKV_ + h*128 + l4*8;
    #pragma unroll
    for (int f = 0; f < 4; ++f) qf[g][f] = *(const bf16x8*)(qp + f*32);
  }

  f32x4 O[2][8];
  #pragma unroll
  for (int g = 0; g < 2; ++g)
    #pragma unroll
    for (int i = 0; i < 8; ++i) O[g][i] = (f32x4){0.f,0.f,0.f,0.f};
  float mx[2] = {-1e30f,-1e30f}, lsum[2] = {0.f,0.f};

  unsigned short* myP = lP + w*(32*64);
  const int ksw = (l15 & 7) << 3;
  const size_t kbase = (size_t)b*S_*NQKV_ + E_ + (size_t)h*128;
  const size_t vbase = (size_t)bh*D_*S_;

  for (int kt = 0; kt < S_; kt += 64) {
    #pragma unroll
    for (int i = 0; i < 4; ++i) {
      int cc = i*256 + tid;
      int row = cc >> 4, col = cc & 15;
      int scol = col ^ (row & 7);
      gload_lds16(qkv + kbase + (size_t)(kt + row)*NQKV_ + scol*8, (char*)lK + cc*16);
    }
    #pragma unroll
    for (int i = 0; i < 4; ++i) {
      int cc = i*256 + tid;
      int row = cc >> 3, col = cc & 7;
      int scol = col ^ ((row & 7) ^ ((row >> 3) & 7));
      gload_lds16(Vt + vbase + (size_t)row*S_ + kt + scol*8, (char*)lV + cc*16);
    }
    asm volatile("s_waitcnt vmcnt(0)" ::: "memory");
    __syncthreads();

    // S^T = K Q^T for both q-groups; kf shared
    f32x4 sfr[2][4];
    #pragma unroll
    for (int nf = 0; nf < 4; ++nf) {
      f32x4 s0 = (f32x4){0.f,0.f,0.f,0.f};
      f32x4 s1 = (f32x4){0.f,0.f,0.f,0.f};
      #pragma unroll
      for (int ks = 0; ks < 4; ++ks) {
        int row = nf*16 + l15;
        int ch = (ks*4 + l4) ^ (row & 7);
        bf16x8 kf = *(const bf16x8*)(lK + row*128 + ch*8);
        s0 = __builtin_amdgcn_mfma_f32_16x16x32_bf16(kf, qf[0][ks], s0, 0, 0, 0);
        s1 = __builtin_amdgcn_mfma_f32_16x16x32_bf16(kf, qf[1][ks], s1, 0, 0, 0);
      }
      sfr[0][nf] = s0; sfr[1][nf] = s1;
    }

    float vm[2];
    #pragma unroll
    for (int g = 0; g < 2; ++g) {
      float v = -1e30f;
      #pragma unroll
      for (int nf = 0; nf < 4; ++nf)
        #pragma unroll
        for (int r = 0; r < 4; ++r) v = fmaxf(v, sfr[g][nf][r]);
      v = fmaxf(v, __shfl_xor(v, 16, 64));
      v = fmaxf(v, __shfl_xor(v, 32, 64));
      vm[g] = v;
    }

    if (__any((vm[0] > mx[0] + 8.0f) || (vm[1] > mx[1] + 8.0f))) {
      #pragma unroll
      for (int g = 0; g < 2; ++g) {
        float mn = fmaxf(mx[g], vm[g]);
        float al = __builtin_amdgcn_exp2f(mx[g] - mn);
        mx[g] = mn;
        lsum[g] *= al;
        #pragma unroll
        for (int r = 0; r < 4; ++r) {
          float ar = __shfl(al, (lane & 48) + l4*4 + r, 64);
          #pragma unroll
          for (int df = 0; df < 8; ++df) O[g][df][r] *= ar;
        }
      }
    }

    #pragma unroll
    for (int g = 0; g < 2; ++g) {
      float ps = 0.f;
      #pragma unroll
      for (int nf = 0; nf < 4; ++nf) {
        #pragma unroll
        for (int r = 0; r < 4; ++r) {
          float p = __builtin_amdgcn_exp2f(sfr[g][nf][r] - mx[g]);
          sfr[g][nf][r] = p;
          ps += p;
        }
      }
      ps += __shfl_xor(ps, 16, 64);
      ps += __shfl_xor(ps, 32, 64);
      lsum[g] += ps;
    }

    // pack P -> bf16 LDS (wave-private 32x64), 8x ds_write_b64
    #pragma unroll
    for (int g = 0; g < 2; ++g) {
      #pragma unroll
      for (int nf = 0; nf < 4; ++nf) {
        unsigned lo = (unsigned)f2bf(sfr[g][nf][0]) | ((unsigned)f2bf(sfr[g][nf][1]) << 16);
        unsigned hi = (unsigned)f2bf(sfr[g][nf][2]) | ((unsigned)f2bf(sfr[g][nf][3]) << 16);
        int k0 = (nf*16 + l4*4) ^ ksw;
        u32x2 val; val[0] = lo; val[1] = hi;
        *(u32x2*)(myP + (g*16 + l15)*64 + k0) = val;
      }
    }
    asm volatile("s_waitcnt lgkmcnt(0)" ::: "memory");

    // O += P V ; vf shared across both q-groups
    #pragma unroll
    for (int ks2 = 0; ks2 < 2; ++ks2) {
      int kk = (ks2*32 + l4*8) ^ ksw;
      bf16x8 pf0 = *(const bf16x8*)(myP + l15*64 + kk);
      bf16x8 pf1 = *(const bf16x8*)(myP + (16 + l15)*64 + kk);
      #pragma unroll
      for (int df = 0; df < 8; ++df) {
        int row = df*16 + l15;
        int ch = (ks2*4 + l4) ^ ((row & 7) ^ ((row >> 3) & 7));
        bf16x8 vf = *(const bf16x8*)(lV + row*64 + ch*8);
        O[0][df] = __builtin_amdgcn_mfma_f32_16x16x32_bf16(pf0, vf, O[0][df], 0, 0, 0);
        O[1][df] = __builtin_amdgcn_mfma_f32_16x16x32_bf16(pf1, vf, O[1][df], 0, 0, 0);
      }
    }
    __syncthreads();
  }

  #pragma unroll
  for (int g = 0; g < 2; ++g) {
    float linv = 1.0f / lsum[g];
    float inv[4];
    #pragma unroll
    for (int r = 0; r < 4; ++r) inv[r] = __shfl(linv, (lane & 48) + l4*4 + r, 64);
    #pragma unroll
    for (int df = 0; df < 8; ++df) {
      int colg = h*128 + df*16 + l15;
      #pragma unroll
      for (int r = 0; r < 4; ++r) {
        int rowg = qt*128 + w*32 + g*16 + l4*4 + r;
        Ao[(size_t)(b*S_ + rowg)*E_ + colg] = f2bf(O[g][df][r] * inv[r]);
      }
    }
  }
}

// ----------------------------------------------------------------
extern "C" void kernel_launch(void* const* d_in, const int* in_sizes, int n_in,
                              void* d_out, int out_size, void* d_ws, size_t ws_size,
                              hipStream_t stream) {
  const float* hs = (const float*)d_in[0];
  const float* Wq = (const float*)d_in[1];
  const float* bq = (const float*)d_in[2];
  const float* Wk = (const float*)d_in[3];
  const float* bk = (const float*)d_in[4];
  const float* Wv = (const float*)d_in[5];
  const float* bv = (const float*)d_in[6];
  const float* Wo = (const float*)d_in[7];
  const float* bo = (const float*)d_in[8];
  float* out = (float*)d_out;

  char* p = (char*)d_ws;
  auto alloc = [&](size_t bytes) { char* r = p; p += (bytes + 255) & ~(size_t)255; return r; };
  unsigned short* hsb  = (unsigned short*)alloc((size_t)M_*E_*2);
  unsigned short* Wqkv = (unsigned short*)alloc((size_t)NQKV_*E_*2);
  unsigned short* Wob  = (unsigned short*)alloc((size_t)E_*E_*2);
  unsigned short* qkv  = (unsigned short*)alloc((size_t)M_*NQKV_*2);
  unsigned short* Vt   = (unsigned short*)alloc((size_t)B_*H_*D_*S_*2);
  unsigned short* Ao   = (unsigned short*)alloc((size_t)M_*E_*2);
  float* biasqkv = (float*)alloc((size_t)NQKV_*4);
  float* cosT = (float*)alloc((size_t)S_*64*4);
  float* sinT = (float*)alloc((size_t)S_*64*4);

  prep_kernel<<<dim3(2048, 5), 256, 0, stream>>>(hs, Wq, Wk, Wv, Wo, bq, bk, bv,
      hsb, Wqkv, Wob, biasqkv, cosT, sinT);
  gemm8<<<dim3((M_/256)*(NQKV_/256)), 512, 0, stream>>>(hsb, Wqkv, biasqkv, qkv, M_, NQKV_, E_);
  rope_kernel<<<dim3((M_*H_*64)/256), 256, 0, stream>>>(qkv, cosT, sinT);
  transv_kernel<<<dim3(B_*H_*(D_/32)*(S_/32)), 256, 0, stream>>>(qkv, Vt);
  attn_kernel<<<dim3(B_*H_*(S_/128)), 256, 0, stream>>>(qkv, Vt, Ao);
  gemm_bt<1><<<dim3((M_/128)*(E_/128)), 256, 0, stream>>>(Ao, Wob, bo, out, M_, E_, E_);
}